// Round 20
// baseline (161.727 us; speedup 1.0000x reference)
//
#include <hip/hip_runtime.h>
#include <math.h>

#define N_TOK 2000
#define NH 8
#define NHH 4   // heads per p2 block (2-way head split)
#define HD 32
#define SCALE 25.0f
#define SIM_TH 0.75f
#define EPSF 1e-8f
#define NT 125  // key tiles of 16 (125*16 = 2000 exact)
#define NTS 63  // key-half split: kh=0 -> [0,63), kh=1 -> [63,125)
#define QT 16   // query rows per attn block — ALL 16 MFMA cols real
// 25 * log2(e): exp(25 s - 25) == exp2(fma(s, EXPC, -EXPC)) — saves one
// VALU op per exp vs __expf's separate log2e multiply (v_exp IS exp2).
#define EXPC 36.067376f

typedef _Float16 half2_t __attribute__((ext_vector_type(2)));
typedef _Float16 f16x4 __attribute__((ext_vector_type(4)));
typedef _Float16 f16x8 __attribute__((ext_vector_type(8)));
typedef float f32x4 __attribute__((ext_vector_type(4)));

__device__ __forceinline__ half2_t u2h(unsigned u) {
  return __builtin_bit_cast(half2_t, u);
}
__device__ __forceinline__ unsigned h2u(half2_t h) {
  return __builtin_bit_cast(unsigned, h);
}
__device__ __forceinline__ float expsc(float d) {
  return exp2f(fmaf(d, EXPC, -EXPC));
}

__device__ __forceinline__ float block_max256(float v, float* red) {
#pragma unroll
  for (int off = 32; off > 0; off >>= 1) v = fmaxf(v, __shfl_xor(v, off, 64));
  __syncthreads();
  if ((threadIdx.x & 63) == 0) red[threadIdx.x >> 6] = v;
  __syncthreads();
  return fmaxf(fmaxf(red[0], red[1]), fmaxf(red[2], red[3]));
}
__device__ __forceinline__ float block_sum256(float v, float* red) {
#pragma unroll
  for (int off = 32; off > 0; off >>= 1) v += __shfl_xor(v, off, 64);
  __syncthreads();
  if ((threadIdx.x & 63) == 0) red[threadIdx.x >> 6] = v;
  __syncthreads();
  return (red[0] + red[1]) + (red[2] + red[3]);
}

// ---------------------------------------------------------------------------
// Kernel 0 (UNCHANGED): pack W fp32 [256][768] transposed to f16 Wt[768][256]
// grid = (96, 2), block = 256.
// ---------------------------------------------------------------------------
__global__ __launch_bounds__(256) void wpackT_kernel(
    const float* __restrict__ W_cls, const float* __restrict__ W_reg,
    _Float16* __restrict__ Wt_cls, _Float16* __restrict__ Wt_reg) {
  const int idx = blockIdx.x * 256 + threadIdx.x;  // 0..24575
  const int kc = idx / 768;                        // 0..31 (k chunk of 8)
  const int n = idx % 768;
  const float* __restrict__ W = blockIdx.y ? W_reg : W_cls;
  _Float16* __restrict__ Wt = blockIdx.y ? Wt_reg : Wt_cls;
  uint4 o;
  o.x = h2u((half2_t){(_Float16)W[(kc * 8 + 0) * 768 + n],
                      (_Float16)W[(kc * 8 + 1) * 768 + n]});
  o.y = h2u((half2_t){(_Float16)W[(kc * 8 + 2) * 768 + n],
                      (_Float16)W[(kc * 8 + 3) * 768 + n]});
  o.z = h2u((half2_t){(_Float16)W[(kc * 8 + 4) * 768 + n],
                      (_Float16)W[(kc * 8 + 5) * 768 + n]});
  o.w = h2u((half2_t){(_Float16)W[(kc * 8 + 6) * 768 + n],
                      (_Float16)W[(kc * 8 + 7) * 768 + n]});
  *(uint4*)(Wt + (size_t)n * 256 + kc * 8) = o;
}

// ---------------------------------------------------------------------------
// Kernel 1 (UNCHANGED): MFMA QKV projection. grid = (125, 5), block 256.
// ---------------------------------------------------------------------------
__global__ __launch_bounds__(256) void qkv_mfma_kernel(
    const float* __restrict__ x_cls, const float* __restrict__ x_reg,
    const _Float16* __restrict__ Wt_cls, const _Float16* __restrict__ Wt_reg,
    _Float16* __restrict__ qc2, _Float16* __restrict__ qr2,
    _Float16* __restrict__ kc2, _Float16* __restrict__ kr2,
    _Float16* __restrict__ vn2, float* __restrict__ v_rm,
    _Float16* __restrict__ v_t) {
  __shared__ _Float16 xs[16][264];  // +8 pad: token stride 528B -> <=2-way

  const int tid = threadIdx.x;
  const int c = blockIdx.y;
  const int which = (c >= 3) ? 1 : 0;
  const int sec = which ? (c - 3) : c;  // 0=q, 1=k, 2=v(cls only)
  const int n0 = sec * 256;
  const int i0 = blockIdx.x * 16;
  const float* __restrict__ x = which ? x_reg : x_cls;
  const _Float16* __restrict__ Wt = which ? Wt_reg : Wt_cls;

  // ---- stage x: 16 tokens x 256 k, f32 -> f16 ----
  {
    const int tok = tid >> 4, c4 = tid & 15;
    const float4* __restrict__ xr =
        (const float4*)(x + (size_t)(i0 + tok) * 256);
#pragma unroll
    for (int r = 0; r < 4; r++) {
      const float4 v = xr[c4 + 16 * r];
      *(unsigned*)&xs[tok][(c4 + 16 * r) * 4] =
          h2u((half2_t){(_Float16)v.x, (_Float16)v.y});
      *(unsigned*)&xs[tok][(c4 + 16 * r) * 4 + 2] =
          h2u((half2_t){(_Float16)v.z, (_Float16)v.w});
    }
  }
  __syncthreads();

  const int w = tid >> 6, l = tid & 63;
  const int q = l & 15, kg = l >> 4;
  const f32x4 zero4 = {0.f, 0.f, 0.f, 0.f};
  f32x4 acc[4] = {zero4, zero4, zero4, zero4};
  const int nb = n0 + w * 64;

#pragma unroll
  for (int ks = 0; ks < 8; ks++) {
    const int k0 = ks * 32;
    const f16x8 bx = *(const f16x8*)&xs[q][k0 + kg * 8];
#pragma unroll
    for (int t2 = 0; t2 < 4; t2++) {
      const f16x8 aw = *(const f16x8*)(
          Wt + (size_t)(nb + t2 * 16 + q) * 256 + k0 + kg * 8);
      acc[t2] =
          __builtin_amdgcn_mfma_f32_16x16x32_f16(aw, bx, acc[t2], 0, 0, 0);
    }
  }

  // ---- l2norm sums: group0 = tiles {0,1}, group1 = tiles {2,3} ----
  float ss0 = 0.f, ss1 = 0.f;
#pragma unroll
  for (int i = 0; i < 4; i++) {
    ss0 += acc[0][i] * acc[0][i] + acc[1][i] * acc[1][i];
    ss1 += acc[2][i] * acc[2][i] + acc[3][i] * acc[3][i];
  }
  ss0 += __shfl_xor(ss0, 16, 64);
  ss0 += __shfl_xor(ss0, 32, 64);
  ss1 += __shfl_xor(ss1, 16, 64);
  ss1 += __shfl_xor(ss1, 32, 64);
  const float inv0 = 1.0f / (sqrtf(ss0) + EPSF);
  const float inv1 = 1.0f / (sqrtf(ss1) + EPSF);

  const int tok = i0 + q;
#pragma unroll
  for (int t2 = 0; t2 < 4; t2++) {
    const float inv = (t2 < 2) ? inv0 : inv1;
    const int nrel = w * 64 + t2 * 16 + kg * 4;  // + i
    const int h = nrel >> 5, d0 = nrel & 31;
    uint2 un;
    un.x = h2u((half2_t){(_Float16)(acc[t2][0] * inv),
                         (_Float16)(acc[t2][1] * inv)});
    un.y = h2u((half2_t){(_Float16)(acc[t2][2] * inv),
                         (_Float16)(acc[t2][3] * inv)});
    const size_t off = ((size_t)(h * N_TOK) + tok) * 32 + d0;
    if (sec == 0) {
      *(uint2*)((which ? qr2 : qc2) + off) = un;
    } else if (sec == 1) {
      *(uint2*)((which ? kr2 : kc2) + off) = un;
    } else {
      *(uint2*)(vn2 + off) = un;
      const float4 vr = {acc[t2][0], acc[t2][1], acc[t2][2], acc[t2][3]};
      *(float4*)(v_rm + off) = vr;
#pragma unroll
      for (int i = 0; i < 4; i++) {
        v_t[((size_t)(h * 32) + d0 + i) * N_TOK + tok] = (_Float16)acc[t2][i];
      }
    }
  }
}

// ---------------------------------------------------------------------------
// Kernel 2a (r40 -> r41): pass 1, r36 form (grid 1000, 2 heads/block,
// key-split) with the exp2f fold. b = qgrp*8 + hp*2 + kh.
// grid = 1000, block = 256.
// ---------------------------------------------------------------------------
__global__ __launch_bounds__(256) void attn_p1_kernel(
    const _Float16* __restrict__ qc2, const _Float16* __restrict__ qr2,
    const _Float16* __restrict__ kc2, const _Float16* __restrict__ kr2,
    float* __restrict__ sums_ws) {
  __shared__ _Float16 qst[2][2][QT][40];
  __shared__ float sums_l[4][2][2][16];

  const int tid = threadIdx.x;
  const int w = tid >> 6;
  const int l = tid & 63;
  const int qgrp = blockIdx.x >> 3;
  const int hp = (blockIdx.x >> 1) & 3;
  const int kh = blockIdx.x & 1;
  const int hq = hp * 2;
  const int i0 = qgrp * QT;

  if (tid < 128) {
    const int hh = tid >> 6, row = (tid >> 2) & 15, dg = tid & 3;
    const size_t src =
        ((size_t)((hq + hh) * N_TOK) + (i0 + row)) * HD + dg * 8;
    *(uint4*)&qst[0][hh][row][dg * 8] = *(const uint4*)(qc2 + src);
    *(uint4*)&qst[1][hh][row][dg * 8] = *(const uint4*)(qr2 + src);
  }
  __syncthreads();

  const int q = l & 15, kg = l >> 4;
  const f32x4 zero4 = {0.f, 0.f, 0.f, 0.f};

  float sc[2], sr[2];
#pragma unroll
  for (int hh = 0; hh < 2; hh++) { sc[hh] = 0.f; sr[hh] = 0.f; }

  const int t0 = kh ? NTS : 0;
  const int t1 = kh ? NT : NTS;
  for (int t = t0 + w; t < t1; t += 4) {
    const int mb = t * 16;
#pragma unroll
    for (int hh = 0; hh < 2; hh++) {
      const size_t koff =
          ((size_t)((hq + hh) * N_TOK) + mb + q) * HD + kg * 8;
      const f16x8 akc = *(const f16x8*)(kc2 + koff);
      const f16x8 akr = *(const f16x8*)(kr2 + koff);
      const f16x8 bqc = *(const f16x8*)&qst[0][hh][q][kg * 8];
      const f16x8 bqr = *(const f16x8*)&qst[1][hh][q][kg * 8];
      const f32x4 dc =
          __builtin_amdgcn_mfma_f32_16x16x32_f16(akc, bqc, zero4, 0, 0, 0);
      const f32x4 dr =
          __builtin_amdgcn_mfma_f32_16x16x32_f16(akr, bqr, zero4, 0, 0, 0);
#pragma unroll
      for (int i = 0; i < 4; i++) {
        sc[hh] += expsc(dc[i]);
        sr[hh] += expsc(dr[i]);
      }
    }
  }
#pragma unroll
  for (int hh = 0; hh < 2; hh++) {
    sc[hh] += __shfl_xor(sc[hh], 16, 64);
    sc[hh] += __shfl_xor(sc[hh], 32, 64);
    sr[hh] += __shfl_xor(sr[hh], 16, 64);
    sr[hh] += __shfl_xor(sr[hh], 32, 64);
  }
  if (l < 16) {
#pragma unroll
    for (int hh = 0; hh < 2; hh++) {
      sums_l[w][0][hh][l] = sc[hh];
      sums_l[w][1][hh][l] = sr[hh];
    }
  }
  __syncthreads();
  if (tid < 64) {
    const int pl = tid >> 5, hh = (tid >> 4) & 1, qq = tid & 15;
    const float s = sums_l[0][pl][hh][qq] + sums_l[1][pl][hh][qq] +
                    sums_l[2][pl][hh][qq] + sums_l[3][pl][hh][qq];
    sums_ws[((size_t)(kh * 2 + pl) * NH + hq + hh) * N_TOK + i0 + qq] = s;
  }
}

// ---------------------------------------------------------------------------
// Kernel 2b (r40 -> r41): pass 2, NHH=4 + key-split, 256t, exp2f fold.
// PV reduce in 2 head-groups of 2 -> pv_ws[kh]; sim/raw: 2 partial planes.
// grid = 500, block = 256.
// ---------------------------------------------------------------------------
__global__ __launch_bounds__(256) void attn_p2_kernel(
    const _Float16* __restrict__ qc2, const _Float16* __restrict__ qr2,
    const _Float16* __restrict__ kc2, const _Float16* __restrict__ kr2,
    const _Float16* __restrict__ vn2, const _Float16* __restrict__ v_t,
    const float* __restrict__ sums_ws, float* __restrict__ pv_ws,
    _Float16* __restrict__ sim_ws, _Float16* __restrict__ raw_ws) {
  __shared__ _Float16 qst[3][NHH][QT][40];  // 15.4 KB
  __shared__ float smem_u[4224];            // 16.9 KB union

  float* __restrict__ nrm = smem_u + 4096;  // [2][NHH][16] = 128 f (tail)
  float* __restrict__ st = smem_u;          // [4][16][20] = 1280 f
  float* __restrict__ pvr = smem_u;         // [4][2][16][33] = 4224 f
  // nrm tail overlaps pvr's end; pvr written only after the loop when
  // ncr/nrr already live in registers.

  const int tid = threadIdx.x;
  const int w = tid >> 6;
  const int l = tid & 63;
  const int qgrp = blockIdx.x >> 2;
  const int hp = (blockIdx.x >> 1) & 1;
  const int kh = blockIdx.x & 1;
  const int hq = hp * NHH;
  const int i0 = qgrp * QT;
  _Float16* __restrict__ simp = sim_ws + (size_t)hp * N_TOK * N_TOK;
  _Float16* __restrict__ rawp = raw_ws + (size_t)hp * N_TOK * N_TOK;

  // ---- stage Q: 3 planes x 4 heads x 16 rows x 32 d ----
  {
    const int hh = tid >> 6, row = (tid >> 2) & 15, dg = tid & 3;
    const size_t src =
        ((size_t)((hq + hh) * N_TOK) + (i0 + row)) * HD + dg * 8;
    *(uint4*)&qst[0][hh][row][dg * 8] = *(const uint4*)(qc2 + src);
    *(uint4*)&qst[1][hh][row][dg * 8] = *(const uint4*)(qr2 + src);
    *(uint4*)&qst[2][hh][row][dg * 8] = *(const uint4*)(vn2 + src);
  }
  // ---- nrm from both key-half partial sums ----
  if (tid < 128) {
    const int pl = tid >> 6, hh = (tid >> 4) & 3, qq = tid & 15;
    const size_t base = ((size_t)pl * NH + hq + hh) * N_TOK + i0 + qq;
    const float s =
        sums_ws[base] + sums_ws[(size_t)2 * NH * N_TOK + base];
    nrm[(pl * NHH + hh) * 16 + qq] = 0.5f / s;
  }
  __syncthreads();

  const int q = l & 15;
  const int kg = l >> 4;
  const int i_glob = i0 + q;
  const int bs = (i_glob / 10) * 10;

  float ncr[NHH], nrr[NHH];
#pragma unroll
  for (int hh = 0; hh < NHH; hh++) {
    ncr[hh] = nrm[(0 * NHH + hh) * 16 + q];
    nrr[hh] = nrm[(1 * NHH + hh) * 16 + q];
  }
  __syncthreads();  // nrm reads done -> st region free; pvr after loop

  const f32x4 zero4 = {0.f, 0.f, 0.f, 0.f};
  f32x4 pv[NHH][2];
#pragma unroll
  for (int hh = 0; hh < NHH; hh++) { pv[hh][0] = zero4; pv[hh][1] = zero4; }

  const int t0 = kh ? NTS : 0;
  const int t1 = kh ? NT : NTS;
  for (int t = t0 + w; t < t1; t += 4) {
    const int mb = t * 16;
    f32x4 simt = zero4;
    f32x4 rawt = zero4;
#pragma unroll
    for (int hh = 0; hh < NHH; hh++) {
      const int h = hq + hh;
      const size_t koff = ((size_t)(h * N_TOK) + mb + q) * HD + kg * 8;
      const f16x8 akc = *(const f16x8*)(kc2 + koff);
      const f16x8 akr = *(const f16x8*)(kr2 + koff);
      const f16x8 avn = *(const f16x8*)(vn2 + koff);
      const f16x8 bqc = *(const f16x8*)&qst[0][hh][q][kg * 8];
      const f16x8 bqr = *(const f16x8*)&qst[1][hh][q][kg * 8];
      const f16x8 bqv = *(const f16x8*)&qst[2][hh][q][kg * 8];
      const f32x4 dc =
          __builtin_amdgcn_mfma_f32_16x16x32_f16(akc, bqc, zero4, 0, 0, 0);
      const f32x4 dr =
          __builtin_amdgcn_mfma_f32_16x16x32_f16(akr, bqr, zero4, 0, 0, 0);
      rawt = __builtin_amdgcn_mfma_f32_16x16x32_f16(avn, bqv, rawt, 0, 0, 0);

      f16x4 pa;
#pragma unroll
      for (int i = 0; i < 4; i++) {
        const float ec = expsc(dc[i]);
        const float er = expsc(dr[i]);
        float ai = ncr[hh] * ec + nrr[hh] * er;
        const int m = mb + kg * 4 + i;
        if (m >= bs && m < bs + 9 && m != i_glob) ai = 0.f;
        simt[i] += ai;
        pa[i] = (_Float16)ai;
      }
      const f16x4 bv0 = *(const f16x4*)(
          v_t + ((size_t)(h * HD) + q) * N_TOK + mb + kg * 4);
      const f16x4 bv1 = *(const f16x4*)(
          v_t + ((size_t)(h * HD) + 16 + q) * N_TOK + mb + kg * 4);
      pv[hh][0] =
          __builtin_amdgcn_mfma_f32_16x16x16f16(pa, bv0, pv[hh][0], 0, 0, 0);
      pv[hh][1] =
          __builtin_amdgcn_mfma_f32_16x16x16f16(pa, bv1, pv[hh][1], 0, 0, 0);
    }
    // ---- stream partial sim tile (f16): 16 rows x 16 cols per wave ----
    st[(w * 16 + q) * 20 + kg * 4 + 0] = simt[0];
    st[(w * 16 + q) * 20 + kg * 4 + 1] = simt[1];
    st[(w * 16 + q) * 20 + kg * 4 + 2] = simt[2];
    st[(w * 16 + q) * 20 + kg * 4 + 3] = simt[3];
    {
      const int row = l >> 2, mo = (l & 3) * 4;
      const float4 v4 = *(const float4*)&st[(w * 16 + row) * 20 + mo];
      uint2 u;
      u.x = h2u((half2_t){(_Float16)v4.x, (_Float16)v4.y});
      u.y = h2u((half2_t){(_Float16)v4.z, (_Float16)v4.w});
      *(uint2*)(simp + (size_t)(i0 + row) * N_TOK + mb + mo) = u;
    }
    // ---- stream partial raw tile (f16) ----
    st[(w * 16 + q) * 20 + kg * 4 + 0] = rawt[0];
    st[(w * 16 + q) * 20 + kg * 4 + 1] = rawt[1];
    st[(w * 16 + q) * 20 + kg * 4 + 2] = rawt[2];
    st[(w * 16 + q) * 20 + kg * 4 + 3] = rawt[3];
    {
      const int row = l >> 2, mo = (l & 3) * 4;
      const float4 v4 = *(const float4*)&st[(w * 16 + row) * 20 + mo];
      uint2 u;
      u.x = h2u((half2_t){(_Float16)v4.x, (_Float16)v4.y});
      u.y = h2u((half2_t){(_Float16)v4.z, (_Float16)v4.w});
      *(uint2*)(rawp + (size_t)(i0 + row) * N_TOK + mb + mo) = u;
    }
  }

  // ======== PV cross-wave reduction -> pv_ws[kh], 2 head-groups of 2 ======
#pragma unroll
  for (int hg = 0; hg < 2; hg++) {
    __syncthreads();  // st reads / previous group's pvr reads done
#pragma unroll
    for (int h2 = 0; h2 < 2; h2++) {
      const int hh = hg * 2 + h2;
#pragma unroll
      for (int i = 0; i < 4; i++) {
        pvr[((w * 2 + h2) * 16 + kg * 4 + i) * 33 + q] = pv[hh][0][i];
        pvr[((w * 2 + h2) * 16 + kg * 4 + i) * 33 + 16 + q] = pv[hh][1][i];
      }
    }
    __syncthreads();
    {
      const int h2 = tid >> 7, qg2 = (tid >> 5) & 3, d = tid & 31;
#pragma unroll
      for (int qi = 0; qi < 4; qi++) {
        const int qq = qg2 * 4 + qi;
        float s = 0.f;
#pragma unroll
        for (int wv = 0; wv < 4; wv++) {
          s += pvr[((wv * 2 + h2) * 16 + qq) * 33 + d];
        }
        pv_ws[(size_t)kh * N_TOK * 256 + (size_t)(i0 + qq) * 256 +
              (hq + hg * 2 + h2) * 32 + d] = s;
      }
    }
  }
}

// ---------------------------------------------------------------------------
// Kernel 3 (r40, UNCHANGED): sim_round2 + out_x assembly; 2 partial planes.
// grid = 1000, block = 256; 2 rows per block.
// ---------------------------------------------------------------------------
__global__ __launch_bounds__(256) void sim_round2_kernel(
    const _Float16* __restrict__ sim_ws, const _Float16* __restrict__ raw_ws,
    const float* __restrict__ pv_ws, const float* __restrict__ v_rm,
    float* __restrict__ out_x, float* __restrict__ out_sim) {
  __shared__ float red[16];
  const int tid = threadIdx.x;
  const size_t NN = (size_t)N_TOK * N_TOK;
  const size_t PVN = (size_t)N_TOK * 256;
  const bool act = tid < 250;
#pragma unroll
  for (int r = 0; r < 2; r++) {
    const int i = blockIdx.x * 2 + r;
    // ---- out_x assembly: attn half = pv halves sum; copy half = v_rm ----
    out_x[(size_t)i * 512 + tid] =
        pv_ws[(size_t)i * 256 + tid] + pv_ws[PVN + (size_t)i * 256 + tid];
    out_x[(size_t)i * 512 + 256 + tid] =
        v_rm[((size_t)(tid >> 5) * N_TOK + i) * 32 + (tid & 31)];

    float s[8], rw[8];
    if (act) {
      const size_t base = (size_t)i * N_TOK + tid * 8;
      const f16x8 s0 = *(const f16x8*)(sim_ws + base);
      const f16x8 s1 = *(const f16x8*)(sim_ws + NN + base);
      const f16x8 r0 = *(const f16x8*)(raw_ws + base);
      const f16x8 r1 = *(const f16x8*)(raw_ws + NN + base);
#pragma unroll
      for (int e = 0; e < 8; e++) {
        s[e] = ((float)s0[e] + (float)s1[e]) * 0.125f;
        rw[e] = (float)r0[e] + (float)r1[e];
      }
    } else {
#pragma unroll
      for (int e = 0; e < 8; e++) { s[e] = -1e30f; rw[e] = 0.f; }
    }
    float lm = -1e30f;
#pragma unroll
    for (int e = 0; e < 8; e++) lm = fmaxf(lm, s[e]);
    const float M = block_max256(lm, red);
    float ls = 0.f;
#pragma unroll
    for (int e = 0; e < 8; e++) {
      const float ev = __expf(s[e] - M);
      s[e] = ev;
      ls += ev;
    }
    const float S = block_sum256(ls, red);
    const float invS = 1.0f / S;
    float lms = 0.f;
#pragma unroll
    for (int e = 0; e < 8; e++) {
      const float p = s[e] * invS;
      const float mp = (act && (rw[e] * 0.125f > SIM_TH)) ? p : 0.f;
      s[e] = mp;
      lms += mp;
    }
    const float MS = block_sum256(lms, red);
    const float invMS = 1.0f / (MS + EPSF);
    if (act) {
      float* __restrict__ outp = out_sim + (size_t)i * N_TOK + tid * 8;
      const float4 o0 = {s[0] * invMS, s[1] * invMS, s[2] * invMS,
                         s[3] * invMS};
      const float4 o1 = {s[4] * invMS, s[5] * invMS, s[6] * invMS,
                         s[7] * invMS};
      *(float4*)outp = o0;
      *(float4*)(outp + 4) = o1;
    }
  }
}

// ---------------------------------------------------------------------------
extern "C" void kernel_launch(void* const* d_in, const int* in_sizes, int n_in,
                              void* d_out, int out_size, void* d_ws,
                              size_t ws_size, hipStream_t stream) {
  const float* x_cls = (const float*)d_in[0];
  const float* x_reg = (const float*)d_in[1];
  const float* W_cls = (const float*)d_in[2];
  const float* W_reg = (const float*)d_in[3];

  // ws layout (~50 MB): v_rm f32, 6 f16 planes, sim f16 x2 partials, raw
  // f16 x2 partials, Wt f16 x2, sums_ws f32, pv_ws f32 x2.
  const size_t seg = (size_t)NH * N_TOK * HD;  // 512000 elements
  float* v_rm = (float*)d_ws;
  _Float16* qc2 = (_Float16*)(v_rm + seg);
  _Float16* qr2 = qc2 + seg;
  _Float16* kc2 = qr2 + seg;
  _Float16* kr2 = kc2 + seg;
  _Float16* vn2 = kr2 + seg;
  _Float16* v_t = vn2 + seg;
  _Float16* sim_ws = v_t + seg;  // 2 x N*N f16
  _Float16* raw_ws = sim_ws + 2 * (size_t)N_TOK * N_TOK;  // 2 x N*N f16
  _Float16* Wt_cls = raw_ws + 2 * (size_t)N_TOK * N_TOK;  // [768][256] f16
  _Float16* Wt_reg = Wt_cls + 768 * 256;
  float* sums_ws = (float*)(Wt_reg + 768 * 256);  // [2kh][2pl][8h][2000] f32
  float* pv_ws = sums_ws + 4 * NH * N_TOK;        // [2kh][2000][256] f32

  dim3 g0(96, 2);
  wpackT_kernel<<<g0, 256, 0, stream>>>(W_cls, W_reg, Wt_cls, Wt_reg);

  dim3 g1(125, 5);
  qkv_mfma_kernel<<<g1, 256, 0, stream>>>(x_cls, x_reg, Wt_cls, Wt_reg, qc2,
                                          qr2, kc2, kr2, vn2, v_rm, v_t);

  float* out_x = (float*)d_out;                  // [2000, 512]
  float* out_sim = out_x + (size_t)N_TOK * 512;  // [2000, 2000]
  attn_p1_kernel<<<1000, 256, 0, stream>>>(qc2, qr2, kc2, kr2, sums_ws);
  attn_p2_kernel<<<500, 256, 0, stream>>>(qc2, qr2, kc2, kr2, vn2, v_t,
                                          sums_ws, pv_ws, sim_ws, raw_ws);
  sim_round2_kernel<<<1000, 256, 0, stream>>>(sim_ws, raw_ws, pv_ws, v_rm,
                                              out_x, out_sim);
}

// Round 21
// 153.920 us; speedup vs baseline: 1.0507x; 1.0507x over previous
//
#include <hip/hip_runtime.h>
#include <math.h>

#define N_TOK 2000
#define NH 8
#define NHH 4   // heads per p2 block (2-way head split)
#define HD 32
#define SCALE 25.0f
#define SIM_TH 0.75f
#define EPSF 1e-8f
#define NT 125  // key tiles of 16 (125*16 = 2000 exact)
#define NTS 63  // key-half split: kh=0 -> [0,63), kh=1 -> [63,125)
#define QT 16   // query rows per attn block — ALL 16 MFMA cols real

typedef _Float16 half2_t __attribute__((ext_vector_type(2)));
typedef _Float16 f16x4 __attribute__((ext_vector_type(4)));
typedef _Float16 f16x8 __attribute__((ext_vector_type(8)));
typedef float f32x4 __attribute__((ext_vector_type(4)));

__device__ __forceinline__ half2_t u2h(unsigned u) {
  return __builtin_bit_cast(half2_t, u);
}
__device__ __forceinline__ unsigned h2u(half2_t h) {
  return __builtin_bit_cast(unsigned, h);
}

__device__ __forceinline__ float block_max256(float v, float* red) {
#pragma unroll
  for (int off = 32; off > 0; off >>= 1) v = fmaxf(v, __shfl_xor(v, off, 64));
  __syncthreads();
  if ((threadIdx.x & 63) == 0) red[threadIdx.x >> 6] = v;
  __syncthreads();
  return fmaxf(fmaxf(red[0], red[1]), fmaxf(red[2], red[3]));
}
__device__ __forceinline__ float block_sum256(float v, float* red) {
#pragma unroll
  for (int off = 32; off > 0; off >>= 1) v += __shfl_xor(v, off, 64);
  __syncthreads();
  if ((threadIdx.x & 63) == 0) red[threadIdx.x >> 6] = v;
  __syncthreads();
  return (red[0] + red[1]) + (red[2] + red[3]);
}

// ---------------------------------------------------------------------------
// Kernel 0: pack W fp32 [256][768] transposed to f16 Wt[768][256].
// grid = (96, 2), block = 256.
// ---------------------------------------------------------------------------
__global__ __launch_bounds__(256) void wpackT_kernel(
    const float* __restrict__ W_cls, const float* __restrict__ W_reg,
    _Float16* __restrict__ Wt_cls, _Float16* __restrict__ Wt_reg) {
  const int idx = blockIdx.x * 256 + threadIdx.x;  // 0..24575
  const int kc = idx / 768;                        // 0..31 (k chunk of 8)
  const int n = idx % 768;
  const float* __restrict__ W = blockIdx.y ? W_reg : W_cls;
  _Float16* __restrict__ Wt = blockIdx.y ? Wt_reg : Wt_cls;
  uint4 o;
  o.x = h2u((half2_t){(_Float16)W[(kc * 8 + 0) * 768 + n],
                      (_Float16)W[(kc * 8 + 1) * 768 + n]});
  o.y = h2u((half2_t){(_Float16)W[(kc * 8 + 2) * 768 + n],
                      (_Float16)W[(kc * 8 + 3) * 768 + n]});
  o.z = h2u((half2_t){(_Float16)W[(kc * 8 + 4) * 768 + n],
                      (_Float16)W[(kc * 8 + 5) * 768 + n]});
  o.w = h2u((half2_t){(_Float16)W[(kc * 8 + 6) * 768 + n],
                      (_Float16)W[(kc * 8 + 7) * 768 + n]});
  *(uint4*)(Wt + (size_t)n * 256 + kc * 8) = o;
}

// ---------------------------------------------------------------------------
// Kernel 1: MFMA QKV projection. grid = (125, 5), block 256.
// ---------------------------------------------------------------------------
__global__ __launch_bounds__(256) void qkv_mfma_kernel(
    const float* __restrict__ x_cls, const float* __restrict__ x_reg,
    const _Float16* __restrict__ Wt_cls, const _Float16* __restrict__ Wt_reg,
    _Float16* __restrict__ qc2, _Float16* __restrict__ qr2,
    _Float16* __restrict__ kc2, _Float16* __restrict__ kr2,
    _Float16* __restrict__ vn2, float* __restrict__ v_rm,
    _Float16* __restrict__ v_t) {
  __shared__ _Float16 xs[16][264];  // +8 pad: token stride 528B -> <=2-way

  const int tid = threadIdx.x;
  const int c = blockIdx.y;
  const int which = (c >= 3) ? 1 : 0;
  const int sec = which ? (c - 3) : c;  // 0=q, 1=k, 2=v(cls only)
  const int n0 = sec * 256;
  const int i0 = blockIdx.x * 16;
  const float* __restrict__ x = which ? x_reg : x_cls;
  const _Float16* __restrict__ Wt = which ? Wt_reg : Wt_cls;

  // ---- stage x: 16 tokens x 256 k, f32 -> f16 ----
  {
    const int tok = tid >> 4, c4 = tid & 15;
    const float4* __restrict__ xr =
        (const float4*)(x + (size_t)(i0 + tok) * 256);
#pragma unroll
    for (int r = 0; r < 4; r++) {
      const float4 v = xr[c4 + 16 * r];
      *(unsigned*)&xs[tok][(c4 + 16 * r) * 4] =
          h2u((half2_t){(_Float16)v.x, (_Float16)v.y});
      *(unsigned*)&xs[tok][(c4 + 16 * r) * 4 + 2] =
          h2u((half2_t){(_Float16)v.z, (_Float16)v.w});
    }
  }
  __syncthreads();

  const int w = tid >> 6, l = tid & 63;
  const int q = l & 15, kg = l >> 4;
  const f32x4 zero4 = {0.f, 0.f, 0.f, 0.f};
  f32x4 acc[4] = {zero4, zero4, zero4, zero4};
  const int nb = n0 + w * 64;

#pragma unroll
  for (int ks = 0; ks < 8; ks++) {
    const int k0 = ks * 32;
    const f16x8 bx = *(const f16x8*)&xs[q][k0 + kg * 8];
#pragma unroll
    for (int t2 = 0; t2 < 4; t2++) {
      const f16x8 aw = *(const f16x8*)(
          Wt + (size_t)(nb + t2 * 16 + q) * 256 + k0 + kg * 8);
      acc[t2] =
          __builtin_amdgcn_mfma_f32_16x16x32_f16(aw, bx, acc[t2], 0, 0, 0);
    }
  }

  // ---- l2norm sums: group0 = tiles {0,1}, group1 = tiles {2,3} ----
  float ss0 = 0.f, ss1 = 0.f;
#pragma unroll
  for (int i = 0; i < 4; i++) {
    ss0 += acc[0][i] * acc[0][i] + acc[1][i] * acc[1][i];
    ss1 += acc[2][i] * acc[2][i] + acc[3][i] * acc[3][i];
  }
  ss0 += __shfl_xor(ss0, 16, 64);
  ss0 += __shfl_xor(ss0, 32, 64);
  ss1 += __shfl_xor(ss1, 16, 64);
  ss1 += __shfl_xor(ss1, 32, 64);
  const float inv0 = 1.0f / (sqrtf(ss0) + EPSF);
  const float inv1 = 1.0f / (sqrtf(ss1) + EPSF);

  const int tok = i0 + q;
#pragma unroll
  for (int t2 = 0; t2 < 4; t2++) {
    const float inv = (t2 < 2) ? inv0 : inv1;
    const int nrel = w * 64 + t2 * 16 + kg * 4;  // + i
    const int h = nrel >> 5, d0 = nrel & 31;
    uint2 un;
    un.x = h2u((half2_t){(_Float16)(acc[t2][0] * inv),
                         (_Float16)(acc[t2][1] * inv)});
    un.y = h2u((half2_t){(_Float16)(acc[t2][2] * inv),
                         (_Float16)(acc[t2][3] * inv)});
    const size_t off = ((size_t)(h * N_TOK) + tok) * 32 + d0;
    if (sec == 0) {
      *(uint2*)((which ? qr2 : qc2) + off) = un;
    } else if (sec == 1) {
      *(uint2*)((which ? kr2 : kc2) + off) = un;
    } else {
      *(uint2*)(vn2 + off) = un;
      const float4 vr = {acc[t2][0], acc[t2][1], acc[t2][2], acc[t2][3]};
      *(float4*)(v_rm + off) = vr;
#pragma unroll
      for (int i = 0; i < 4; i++) {
        v_t[((size_t)(h * 32) + d0 + i) * N_TOK + tok] = (_Float16)acc[t2][i];
      }
    }
  }
}

// ---------------------------------------------------------------------------
// Kernel 2a: pass 1, r36 form (grid 1000, 2 heads/block, key-split).
// b = qgrp*8 + hp*2 + kh. grid = 1000, block = 256.
// ---------------------------------------------------------------------------
__global__ __launch_bounds__(256) void attn_p1_kernel(
    const _Float16* __restrict__ qc2, const _Float16* __restrict__ qr2,
    const _Float16* __restrict__ kc2, const _Float16* __restrict__ kr2,
    float* __restrict__ sums_ws) {
  __shared__ _Float16 qst[2][2][QT][40];
  __shared__ float sums_l[4][2][2][16];

  const int tid = threadIdx.x;
  const int w = tid >> 6;
  const int l = tid & 63;
  const int qgrp = blockIdx.x >> 3;
  const int hp = (blockIdx.x >> 1) & 3;
  const int kh = blockIdx.x & 1;
  const int hq = hp * 2;
  const int i0 = qgrp * QT;

  if (tid < 128) {
    const int hh = tid >> 6, row = (tid >> 2) & 15, dg = tid & 3;
    const size_t src =
        ((size_t)((hq + hh) * N_TOK) + (i0 + row)) * HD + dg * 8;
    *(uint4*)&qst[0][hh][row][dg * 8] = *(const uint4*)(qc2 + src);
    *(uint4*)&qst[1][hh][row][dg * 8] = *(const uint4*)(qr2 + src);
  }
  __syncthreads();

  const int q = l & 15, kg = l >> 4;
  const f32x4 zero4 = {0.f, 0.f, 0.f, 0.f};

  float sc[2], sr[2];
#pragma unroll
  for (int hh = 0; hh < 2; hh++) { sc[hh] = 0.f; sr[hh] = 0.f; }

  const int t0 = kh ? NTS : 0;
  const int t1 = kh ? NT : NTS;
  for (int t = t0 + w; t < t1; t += 4) {
    const int mb = t * 16;
#pragma unroll
    for (int hh = 0; hh < 2; hh++) {
      const size_t koff =
          ((size_t)((hq + hh) * N_TOK) + mb + q) * HD + kg * 8;
      const f16x8 akc = *(const f16x8*)(kc2 + koff);
      const f16x8 akr = *(const f16x8*)(kr2 + koff);
      const f16x8 bqc = *(const f16x8*)&qst[0][hh][q][kg * 8];
      const f16x8 bqr = *(const f16x8*)&qst[1][hh][q][kg * 8];
      const f32x4 dc =
          __builtin_amdgcn_mfma_f32_16x16x32_f16(akc, bqc, zero4, 0, 0, 0);
      const f32x4 dr =
          __builtin_amdgcn_mfma_f32_16x16x32_f16(akr, bqr, zero4, 0, 0, 0);
#pragma unroll
      for (int i = 0; i < 4; i++) {
        sc[hh] += __expf(dc[i] * SCALE - SCALE);
        sr[hh] += __expf(dr[i] * SCALE - SCALE);
      }
    }
  }
#pragma unroll
  for (int hh = 0; hh < 2; hh++) {
    sc[hh] += __shfl_xor(sc[hh], 16, 64);
    sc[hh] += __shfl_xor(sc[hh], 32, 64);
    sr[hh] += __shfl_xor(sr[hh], 16, 64);
    sr[hh] += __shfl_xor(sr[hh], 32, 64);
  }
  if (l < 16) {
#pragma unroll
    for (int hh = 0; hh < 2; hh++) {
      sums_l[w][0][hh][l] = sc[hh];
      sums_l[w][1][hh][l] = sr[hh];
    }
  }
  __syncthreads();
  if (tid < 64) {
    const int pl = tid >> 5, hh = (tid >> 4) & 1, qq = tid & 15;
    const float s = sums_l[0][pl][hh][qq] + sums_l[1][pl][hh][qq] +
                    sums_l[2][pl][hh][qq] + sums_l[3][pl][hh][qq];
    sums_ws[((size_t)(kh * 2 + pl) * NH + hq + hh) * N_TOK + i0 + qq] = s;
  }
}

// ---------------------------------------------------------------------------
// Kernel 2b: pass 2, NHH=4 + key-split, 256t; measured 48.5-49.9us.
// PV reduce in 2 head-groups of 2 -> pv_ws[kh]; sim/raw: 2 partial planes.
// grid = 500, block = 256.
// ---------------------------------------------------------------------------
__global__ __launch_bounds__(256) void attn_p2_kernel(
    const _Float16* __restrict__ qc2, const _Float16* __restrict__ qr2,
    const _Float16* __restrict__ kc2, const _Float16* __restrict__ kr2,
    const _Float16* __restrict__ vn2, const _Float16* __restrict__ v_t,
    const float* __restrict__ sums_ws, float* __restrict__ pv_ws,
    _Float16* __restrict__ sim_ws, _Float16* __restrict__ raw_ws) {
  __shared__ _Float16 qst[3][NHH][QT][40];  // 15.4 KB
  __shared__ float smem_u[4224];            // 16.9 KB union

  float* __restrict__ nrm = smem_u + 4096;  // [2][NHH][16] = 128 f (tail)
  float* __restrict__ st = smem_u;          // [4][16][20] = 1280 f
  float* __restrict__ pvr = smem_u;         // [4][2][16][33] = 4224 f
  // nrm tail overlaps pvr's end; pvr written only after the loop when
  // ncr/nrr already live in registers.

  const int tid = threadIdx.x;
  const int w = tid >> 6;
  const int l = tid & 63;
  const int qgrp = blockIdx.x >> 2;
  const int hp = (blockIdx.x >> 1) & 1;
  const int kh = blockIdx.x & 1;
  const int hq = hp * NHH;
  const int i0 = qgrp * QT;
  _Float16* __restrict__ simp = sim_ws + (size_t)hp * N_TOK * N_TOK;
  _Float16* __restrict__ rawp = raw_ws + (size_t)hp * N_TOK * N_TOK;

  // ---- stage Q: 3 planes x 4 heads x 16 rows x 32 d ----
  {
    const int hh = tid >> 6, row = (tid >> 2) & 15, dg = tid & 3;
    const size_t src =
        ((size_t)((hq + hh) * N_TOK) + (i0 + row)) * HD + dg * 8;
    *(uint4*)&qst[0][hh][row][dg * 8] = *(const uint4*)(qc2 + src);
    *(uint4*)&qst[1][hh][row][dg * 8] = *(const uint4*)(qr2 + src);
    *(uint4*)&qst[2][hh][row][dg * 8] = *(const uint4*)(vn2 + src);
  }
  // ---- nrm from both key-half partial sums ----
  if (tid < 128) {
    const int pl = tid >> 6, hh = (tid >> 4) & 3, qq = tid & 15;
    const size_t base = ((size_t)pl * NH + hq + hh) * N_TOK + i0 + qq;
    const float s =
        sums_ws[base] + sums_ws[(size_t)2 * NH * N_TOK + base];
    nrm[(pl * NHH + hh) * 16 + qq] = 0.5f / s;
  }
  __syncthreads();

  const int q = l & 15;
  const int kg = l >> 4;
  const int i_glob = i0 + q;
  const int bs = (i_glob / 10) * 10;

  float ncr[NHH], nrr[NHH];
#pragma unroll
  for (int hh = 0; hh < NHH; hh++) {
    ncr[hh] = nrm[(0 * NHH + hh) * 16 + q];
    nrr[hh] = nrm[(1 * NHH + hh) * 16 + q];
  }
  __syncthreads();  // nrm reads done -> st region free; pvr after loop

  const f32x4 zero4 = {0.f, 0.f, 0.f, 0.f};
  f32x4 pv[NHH][2];
#pragma unroll
  for (int hh = 0; hh < NHH; hh++) { pv[hh][0] = zero4; pv[hh][1] = zero4; }

  const int t0 = kh ? NTS : 0;
  const int t1 = kh ? NT : NTS;
  for (int t = t0 + w; t < t1; t += 4) {
    const int mb = t * 16;
    f32x4 simt = zero4;
    f32x4 rawt = zero4;
#pragma unroll
    for (int hh = 0; hh < NHH; hh++) {
      const int h = hq + hh;
      const size_t koff = ((size_t)(h * N_TOK) + mb + q) * HD + kg * 8;
      const f16x8 akc = *(const f16x8*)(kc2 + koff);
      const f16x8 akr = *(const f16x8*)(kr2 + koff);
      const f16x8 avn = *(const f16x8*)(vn2 + koff);
      const f16x8 bqc = *(const f16x8*)&qst[0][hh][q][kg * 8];
      const f16x8 bqr = *(const f16x8*)&qst[1][hh][q][kg * 8];
      const f16x8 bqv = *(const f16x8*)&qst[2][hh][q][kg * 8];
      const f32x4 dc =
          __builtin_amdgcn_mfma_f32_16x16x32_f16(akc, bqc, zero4, 0, 0, 0);
      const f32x4 dr =
          __builtin_amdgcn_mfma_f32_16x16x32_f16(akr, bqr, zero4, 0, 0, 0);
      rawt = __builtin_amdgcn_mfma_f32_16x16x32_f16(avn, bqv, rawt, 0, 0, 0);

      f16x4 pa;
#pragma unroll
      for (int i = 0; i < 4; i++) {
        const float ec = __expf(dc[i] * SCALE - SCALE);
        const float er = __expf(dr[i] * SCALE - SCALE);
        float ai = ncr[hh] * ec + nrr[hh] * er;
        const int m = mb + kg * 4 + i;
        if (m >= bs && m < bs + 9 && m != i_glob) ai = 0.f;
        simt[i] += ai;
        pa[i] = (_Float16)ai;
      }
      const f16x4 bv0 = *(const f16x4*)(
          v_t + ((size_t)(h * HD) + q) * N_TOK + mb + kg * 4);
      const f16x4 bv1 = *(const f16x4*)(
          v_t + ((size_t)(h * HD) + 16 + q) * N_TOK + mb + kg * 4);
      pv[hh][0] =
          __builtin_amdgcn_mfma_f32_16x16x16f16(pa, bv0, pv[hh][0], 0, 0, 0);
      pv[hh][1] =
          __builtin_amdgcn_mfma_f32_16x16x16f16(pa, bv1, pv[hh][1], 0, 0, 0);
    }
    // ---- stream partial sim tile (f16): 16 rows x 16 cols per wave ----
    st[(w * 16 + q) * 20 + kg * 4 + 0] = simt[0];
    st[(w * 16 + q) * 20 + kg * 4 + 1] = simt[1];
    st[(w * 16 + q) * 20 + kg * 4 + 2] = simt[2];
    st[(w * 16 + q) * 20 + kg * 4 + 3] = simt[3];
    {
      const int row = l >> 2, mo = (l & 3) * 4;
      const float4 v4 = *(const float4*)&st[(w * 16 + row) * 20 + mo];
      uint2 u;
      u.x = h2u((half2_t){(_Float16)v4.x, (_Float16)v4.y});
      u.y = h2u((half2_t){(_Float16)v4.z, (_Float16)v4.w});
      *(uint2*)(simp + (size_t)(i0 + row) * N_TOK + mb + mo) = u;
    }
    // ---- stream partial raw tile (f16) ----
    st[(w * 16 + q) * 20 + kg * 4 + 0] = rawt[0];
    st[(w * 16 + q) * 20 + kg * 4 + 1] = rawt[1];
    st[(w * 16 + q) * 20 + kg * 4 + 2] = rawt[2];
    st[(w * 16 + q) * 20 + kg * 4 + 3] = rawt[3];
    {
      const int row = l >> 2, mo = (l & 3) * 4;
      const float4 v4 = *(const float4*)&st[(w * 16 + row) * 20 + mo];
      uint2 u;
      u.x = h2u((half2_t){(_Float16)v4.x, (_Float16)v4.y});
      u.y = h2u((half2_t){(_Float16)v4.z, (_Float16)v4.w});
      *(uint2*)(rawp + (size_t)(i0 + row) * N_TOK + mb + mo) = u;
    }
  }

  // ======== PV cross-wave reduction -> pv_ws[kh], 2 head-groups of 2 ======
#pragma unroll
  for (int hg = 0; hg < 2; hg++) {
    __syncthreads();  // st reads / previous group's pvr reads done
#pragma unroll
    for (int h2 = 0; h2 < 2; h2++) {
      const int hh = hg * 2 + h2;
#pragma unroll
      for (int i = 0; i < 4; i++) {
        pvr[((w * 2 + h2) * 16 + kg * 4 + i) * 33 + q] = pv[hh][0][i];
        pvr[((w * 2 + h2) * 16 + kg * 4 + i) * 33 + 16 + q] = pv[hh][1][i];
      }
    }
    __syncthreads();
    {
      const int h2 = tid >> 7, qg2 = (tid >> 5) & 3, d = tid & 31;
#pragma unroll
      for (int qi = 0; qi < 4; qi++) {
        const int qq = qg2 * 4 + qi;
        float s = 0.f;
#pragma unroll
        for (int wv = 0; wv < 4; wv++) {
          s += pvr[((wv * 2 + h2) * 16 + qq) * 33 + d];
        }
        pv_ws[(size_t)kh * N_TOK * 256 + (size_t)(i0 + qq) * 256 +
              (hq + hg * 2 + h2) * 32 + d] = s;
      }
    }
  }
}

// ---------------------------------------------------------------------------
// Kernel 3: sim_round2 + out_x assembly; 2 partial planes.
// grid = 1000, block = 256; 2 rows per block.
// ---------------------------------------------------------------------------
__global__ __launch_bounds__(256) void sim_round2_kernel(
    const _Float16* __restrict__ sim_ws, const _Float16* __restrict__ raw_ws,
    const float* __restrict__ pv_ws, const float* __restrict__ v_rm,
    float* __restrict__ out_x, float* __restrict__ out_sim) {
  __shared__ float red[16];
  const int tid = threadIdx.x;
  const size_t NN = (size_t)N_TOK * N_TOK;
  const size_t PVN = (size_t)N_TOK * 256;
  const bool act = tid < 250;
#pragma unroll
  for (int r = 0; r < 2; r++) {
    const int i = blockIdx.x * 2 + r;
    // ---- out_x assembly: attn half = pv halves sum; copy half = v_rm ----
    out_x[(size_t)i * 512 + tid] =
        pv_ws[(size_t)i * 256 + tid] + pv_ws[PVN + (size_t)i * 256 + tid];
    out_x[(size_t)i * 512 + 256 + tid] =
        v_rm[((size_t)(tid >> 5) * N_TOK + i) * 32 + (tid & 31)];

    float s[8], rw[8];
    if (act) {
      const size_t base = (size_t)i * N_TOK + tid * 8;
      const f16x8 s0 = *(const f16x8*)(sim_ws + base);
      const f16x8 s1 = *(const f16x8*)(sim_ws + NN + base);
      const f16x8 r0 = *(const f16x8*)(raw_ws + base);
      const f16x8 r1 = *(const f16x8*)(raw_ws + NN + base);
#pragma unroll
      for (int e = 0; e < 8; e++) {
        s[e] = ((float)s0[e] + (float)s1[e]) * 0.125f;
        rw[e] = (float)r0[e] + (float)r1[e];
      }
    } else {
#pragma unroll
      for (int e = 0; e < 8; e++) { s[e] = -1e30f; rw[e] = 0.f; }
    }
    float lm = -1e30f;
#pragma unroll
    for (int e = 0; e < 8; e++) lm = fmaxf(lm, s[e]);
    const float M = block_max256(lm, red);
    float ls = 0.f;
#pragma unroll
    for (int e = 0; e < 8; e++) {
      const float ev = __expf(s[e] - M);
      s[e] = ev;
      ls += ev;
    }
    const float S = block_sum256(ls, red);
    const float invS = 1.0f / S;
    float lms = 0.f;
#pragma unroll
    for (int e = 0; e < 8; e++) {
      const float p = s[e] * invS;
      const float mp = (act && (rw[e] * 0.125f > SIM_TH)) ? p : 0.f;
      s[e] = mp;
      lms += mp;
    }
    const float MS = block_sum256(lms, red);
    const float invMS = 1.0f / (MS + EPSF);
    if (act) {
      float* __restrict__ outp = out_sim + (size_t)i * N_TOK + tid * 8;
      const float4 o0 = {s[0] * invMS, s[1] * invMS, s[2] * invMS,
                         s[3] * invMS};
      const float4 o1 = {s[4] * invMS, s[5] * invMS, s[6] * invMS,
                         s[7] * invMS};
      *(float4*)outp = o0;
      *(float4*)(outp + 4) = o1;
    }
  }
}

// ---------------------------------------------------------------------------
extern "C" void kernel_launch(void* const* d_in, const int* in_sizes, int n_in,
                              void* d_out, int out_size, void* d_ws,
                              size_t ws_size, hipStream_t stream) {
  const float* x_cls = (const float*)d_in[0];
  const float* x_reg = (const float*)d_in[1];
  const float* W_cls = (const float*)d_in[2];
  const float* W_reg = (const float*)d_in[3];

  // ws layout (~50 MB): v_rm f32, 6 f16 planes, sim f16 x2 partials, raw
  // f16 x2 partials, Wt f16 x2, sums_ws f32, pv_ws f32 x2.
  const size_t seg = (size_t)NH * N_TOK * HD;  // 512000 elements
  float* v_rm = (float*)d_ws;
  _Float16* qc2 = (_Float16*)(v_rm + seg);
  _Float16* qr2 = qc2 + seg;
  _Float16* kc2 = qr2 + seg;
  _Float16* kr2 = kc2 + seg;
  _Float16* vn2 = kr2 + seg;
  _Float16* v_t = vn2 + seg;
  _Float16* sim_ws = v_t + seg;  // 2 x N*N f16
  _Float16* raw_ws = sim_ws + 2 * (size_t)N_TOK * N_TOK;  // 2 x N*N f16
  _Float16* Wt_cls = raw_ws + 2 * (size_t)N_TOK * N_TOK;  // [768][256] f16
  _Float16* Wt_reg = Wt_cls + 768 * 256;
  float* sums_ws = (float*)(Wt_reg + 768 * 256);  // [2kh][2pl][8h][2000] f32
  float* pv_ws = sums_ws + 4 * NH * N_TOK;        // [2kh][2000][256] f32

  dim3 g0(96, 2);
  wpackT_kernel<<<g0, 256, 0, stream>>>(W_cls, W_reg, Wt_cls, Wt_reg);

  dim3 g1(125, 5);
  qkv_mfma_kernel<<<g1, 256, 0, stream>>>(x_cls, x_reg, Wt_cls, Wt_reg, qc2,
                                          qr2, kc2, kr2, vn2, v_rm, v_t);

  float* out_x = (float*)d_out;                  // [2000, 512]
  float* out_sim = out_x + (size_t)N_TOK * 512;  // [2000, 2000]
  attn_p1_kernel<<<1000, 256, 0, stream>>>(qc2, qr2, kc2, kr2, sums_ws);
  attn_p2_kernel<<<500, 256, 0, stream>>>(qc2, qr2, kc2, kr2, vn2, v_t,
                                          sums_ws, pv_ws, sim_ws, raw_ws);
  sim_round2_kernel<<<1000, 256, 0, stream>>>(sim_ws, raw_ws, pv_ws, v_rm,
                                              out_x, out_sim);
}